// Round 1
// baseline (2205.923 us; speedup 1.0000x reference)
//
#include <hip/hip_runtime.h>
#include <math.h>

#define BB 4
#define LL 256
#define DD 768
#define HH 384
#define G4 1536
#define NWIN 4
#define NLIN 9
#define NCHAIN 8
#define NPOS 1024        // B*L
#define PROJ_N 12288     // NCHAIN * G4

// ---------------------------------------------------------------- zero
__global__ void zero_f4(float4* __restrict__ p, int n4) {
    int i = blockIdx.x * blockDim.x + threadIdx.x;
    if (i < n4) p[i] = make_float4(0.f, 0.f, 0.f, 0.f);
}

// ---------------------------------------------------------------- scatter
// x[b, dest[l], :] = seq[b, l, :]  where dest = cumsum(valid)-1 for valid rows.
__global__ void scatter_kernel(const float* __restrict__ seq,
                               const int* __restrict__ valid,
                               float* __restrict__ x) {
    const int b = blockIdx.x >> 3;
    const int chunk = blockIdx.x & 7;
    const int tid = threadIdx.x;
    __shared__ int vbuf[LL];
    __shared__ int dest[LL];
    vbuf[tid] = valid[b * LL + tid];
    __syncthreads();
    if (tid == 0) {
        int c = 0;
        for (int l = 0; l < LL; ++l) dest[l] = vbuf[l] ? c++ : -1;
    }
    __syncthreads();
    for (int l = chunk * 32; l < chunk * 32 + 32; ++l) {
        const int d = dest[l];
        if (d >= 0) {
            const float4* src = (const float4*)(seq + (size_t)(b * LL + l) * DD);
            float4* dst = (float4*)(x + (size_t)(b * LL + d) * DD);
            for (int j = tid; j < DD / 4; j += blockDim.x) dst[j] = src[j];
        }
    }
}

// ---------------------------------------------------------------- proj GEMM
// proj[m][n] = sum_k x[m][k] * Wall[n][k] + bias[n]
// n = chain*1536 + r ; chain = dir*4+wi ; Wall row = w_ih_{f,b}[wi][r][:]
__global__ __launch_bounds__(256) void proj_gemm(
        const float* __restrict__ x,
        const float* __restrict__ wih_f, const float* __restrict__ wih_b,
        const float* __restrict__ bih_f, const float* __restrict__ bhh_f,
        const float* __restrict__ bih_b, const float* __restrict__ bhh_b,
        float* __restrict__ proj) {
    const int n0 = blockIdx.x * 64;
    const int m0 = blockIdx.y * 64;
    const int tid = threadIdx.x;
    const int tx = tid & 15, ty = tid >> 4;
    __shared__ __align__(16) float As[16][68];
    __shared__ __align__(16) float Bs[16][68];
    const int lr = tid >> 2;        // 0..63
    const int lk = (tid & 3) * 4;   // 0,4,8,12
    const int nrow = n0 + lr;
    const int chain = nrow / G4;
    const int rr = nrow % G4;
    const int dirb = chain >> 2, wib = chain & 3;
    const float* wrow = (dirb ? wih_b : wih_f) + (size_t)(wib * G4 + rr) * DD;
    const float* arow = x + (size_t)(m0 + lr) * DD;
    float acc[4][4] = {};
    for (int k0 = 0; k0 < DD; k0 += 16) {
        const float4 av = *(const float4*)(arow + k0 + lk);
        const float4 bv = *(const float4*)(wrow + k0 + lk);
        As[lk + 0][lr] = av.x; As[lk + 1][lr] = av.y;
        As[lk + 2][lr] = av.z; As[lk + 3][lr] = av.w;
        Bs[lk + 0][lr] = bv.x; Bs[lk + 1][lr] = bv.y;
        Bs[lk + 2][lr] = bv.z; Bs[lk + 3][lr] = bv.w;
        __syncthreads();
#pragma unroll
        for (int k = 0; k < 16; ++k) {
            const float4 a = *(const float4*)&As[k][ty * 4];
            const float4 bq = *(const float4*)&Bs[k][tx * 4];
            acc[0][0] = fmaf(a.x, bq.x, acc[0][0]); acc[0][1] = fmaf(a.x, bq.y, acc[0][1]);
            acc[0][2] = fmaf(a.x, bq.z, acc[0][2]); acc[0][3] = fmaf(a.x, bq.w, acc[0][3]);
            acc[1][0] = fmaf(a.y, bq.x, acc[1][0]); acc[1][1] = fmaf(a.y, bq.y, acc[1][1]);
            acc[1][2] = fmaf(a.y, bq.z, acc[1][2]); acc[1][3] = fmaf(a.y, bq.w, acc[1][3]);
            acc[2][0] = fmaf(a.z, bq.x, acc[2][0]); acc[2][1] = fmaf(a.z, bq.y, acc[2][1]);
            acc[2][2] = fmaf(a.z, bq.z, acc[2][2]); acc[2][3] = fmaf(a.z, bq.w, acc[2][3]);
            acc[3][0] = fmaf(a.w, bq.x, acc[3][0]); acc[3][1] = fmaf(a.w, bq.y, acc[3][1]);
            acc[3][2] = fmaf(a.w, bq.z, acc[3][2]); acc[3][3] = fmaf(a.w, bq.w, acc[3][3]);
        }
        __syncthreads();
    }
    // bias (tile never straddles a chain since 1536 % 64 == 0)
    const int colbase = n0 + tx * 4;
    const int chain_c = colbase / G4;
    const int rbase = colbase % G4;
    const int dc = chain_c >> 2, wc = chain_c & 3;
    const float* bi = dc ? bih_b : bih_f;
    const float* bh = dc ? bhh_b : bhh_f;
    float bias[4];
#pragma unroll
    for (int j = 0; j < 4; ++j)
        bias[j] = bi[wc * G4 + rbase + j] + bh[wc * G4 + rbase + j];
#pragma unroll
    for (int i = 0; i < 4; ++i) {
        const int row = m0 + ty * 4 + i;
#pragma unroll
        for (int j = 0; j < 4; ++j)
            proj[(size_t)row * PROJ_N + colbase + j] = acc[i][j] + bias[j];
    }
}

// ---------------------------------------------------------------- recurrence
// One block per (chain, 16-position tile). 384 threads: thread t = hidden unit t.
// h state in LDS (broadcast reads), c state + gate accumulators in registers.
__global__ __launch_bounds__(384) void lstm_rec(
        const float* __restrict__ proj,
        const float* __restrict__ whh_f, const float* __restrict__ whh_b,
        float* __restrict__ hout) {
    const int chain = blockIdx.x & 7;   // chain -> XCD pinning for W_hh L2 reuse
    const int tile = blockIdx.x >> 3;   // 0..63
    const int dir = chain >> 2, wi = chain & 3;
    const int w = 3 + 2 * wi;
    const int half = wi + 1;
    const int P0 = tile * 16;
    const int b = P0 >> 8;
    const int l0 = P0 & 255;
    const int t_ = threadIdx.x;         // hidden index 0..383

    const float* W = (dir ? whh_b : whh_f) + (size_t)wi * G4 * HH;
    const float* Wi = W + (size_t)(0 * HH + t_) * HH;
    const float* Wf = W + (size_t)(1 * HH + t_) * HH;
    const float* Wg = W + (size_t)(2 * HH + t_) * HH;
    const float* Wo = W + (size_t)(3 * HH + t_) * HH;

    __shared__ __align__(16) float h_lds[16][HH];
    for (int i = t_; i < 16 * HH; i += 384) ((float*)h_lds)[i] = 0.f;
    float c[16];
#pragma unroll
    for (int p = 0; p < 16; ++p) c[p] = 0.f;
    __syncthreads();

    for (int s = 0; s < w; ++s) {
        const int t = dir ? (w - 1 - s) : s;
        float ai[16], af[16], ag[16], ao[16];
        bool vld[16];
#pragma unroll
        for (int p = 0; p < 16; ++p) {
            const int pos = l0 + p + t - half;
            vld[p] = (pos >= 0) && (pos < LL);
            const int pc = pos < 0 ? 0 : (pos > LL - 1 ? LL - 1 : pos);
            const int base = (b * LL + pc) * PROJ_N + chain * G4 + t_;
            ai[p] = proj[base];
            af[p] = proj[base + HH];
            ag[p] = proj[base + 2 * HH];
            ao[p] = proj[base + 3 * HH];
        }
#pragma unroll 2
        for (int k0 = 0; k0 < HH; k0 += 4) {
            const float4 wiv = *(const float4*)(Wi + k0);
            const float4 wfv = *(const float4*)(Wf + k0);
            const float4 wgv = *(const float4*)(Wg + k0);
            const float4 wov = *(const float4*)(Wo + k0);
#pragma unroll
            for (int p = 0; p < 16; ++p) {
                const float4 hv = *(const float4*)&h_lds[p][k0];
                ai[p] = fmaf(hv.x, wiv.x, fmaf(hv.y, wiv.y, fmaf(hv.z, wiv.z, fmaf(hv.w, wiv.w, ai[p]))));
                af[p] = fmaf(hv.x, wfv.x, fmaf(hv.y, wfv.y, fmaf(hv.z, wfv.z, fmaf(hv.w, wfv.w, af[p]))));
                ag[p] = fmaf(hv.x, wgv.x, fmaf(hv.y, wgv.y, fmaf(hv.z, wgv.z, fmaf(hv.w, wgv.w, ag[p]))));
                ao[p] = fmaf(hv.x, wov.x, fmaf(hv.y, wov.y, fmaf(hv.z, wov.z, fmaf(hv.w, wov.w, ao[p]))));
            }
        }
        __syncthreads();  // everyone done reading h
        float hn[16];
#pragma unroll
        for (int p = 0; p < 16; ++p) {
            if (vld[p]) {
                const float iv = 1.f / (1.f + __expf(-ai[p]));
                const float fv = 1.f / (1.f + __expf(-af[p]));
                const float gv = tanhf(ag[p]);
                const float ov = 1.f / (1.f + __expf(-ao[p]));
                c[p] = fv * c[p] + iv * gv;
                hn[p] = ov * tanhf(c[p]);
            }
        }
#pragma unroll
        for (int p = 0; p < 16; ++p)
            if (vld[p]) h_lds[p][t_] = hn[p];
        __syncthreads();
    }
#pragma unroll
    for (int p = 0; p < 16; ++p)
        hout[(size_t)(chain * NPOS + P0 + p) * HH + t_] = h_lds[p][t_];
}

// ---------------------------------------------------------------- attention + linear head
__global__ __launch_bounds__(256) void attn_out_kernel(
        const float* __restrict__ x, const float* __restrict__ hout,
        const float* __restrict__ lin_w, const float* __restrict__ lin_b,
        float* __restrict__ out) {
    const int P = blockIdx.x;
    const int tid = threadIdx.x;
    const int lane = tid & 63, wid = tid >> 6;
    __shared__ float sc[NWIN][4];
    __shared__ float attn_s[NWIN];
    __shared__ float ov[DD];
    __shared__ float red[NLIN][4];
    const float inv_sqrt_d = 0.03608439182435161f;  // 1/sqrt(768)

    float xr[3];
#pragma unroll
    for (int j = 0; j < 3; ++j) xr[j] = x[(size_t)P * DD + tid + 256 * j];

#pragma unroll
    for (int wi = 0; wi < NWIN; ++wi) {
        float part = 0.f;
#pragma unroll
        for (int j = 0; j < 3; ++j) {
            const int col = tid + 256 * j;
            const float m = (col < HH)
                ? hout[(size_t)(wi * NPOS + P) * HH + col]
                : hout[(size_t)((4 + wi) * NPOS + P) * HH + col - HH];
            part = fmaf(xr[j], m, part);
        }
        for (int off = 32; off > 0; off >>= 1) part += __shfl_down(part, off);
        if (lane == 0) sc[wi][wid] = part;
    }
    __syncthreads();
    if (tid == 0) {
        float s[NWIN], mx = -1e30f;
        for (int wi = 0; wi < NWIN; ++wi) {
            s[wi] = (sc[wi][0] + sc[wi][1] + sc[wi][2] + sc[wi][3]) * inv_sqrt_d;
            mx = fmaxf(mx, s[wi]);
        }
        float denom = 0.f;
        for (int wi = 0; wi < NWIN; ++wi) { s[wi] = __expf(s[wi] - mx); denom += s[wi]; }
        for (int wi = 0; wi < NWIN; ++wi) attn_s[wi] = s[wi] / denom;
    }
    __syncthreads();
#pragma unroll
    for (int j = 0; j < 3; ++j) {
        const int col = tid + 256 * j;
        float lv = 0.f;
#pragma unroll
        for (int wi = 0; wi < NWIN; ++wi) {
            const float m = (col < HH)
                ? hout[(size_t)(wi * NPOS + P) * HH + col]
                : hout[(size_t)((4 + wi) * NPOS + P) * HH + col - HH];
            lv = fmaf(attn_s[wi], m, lv);
        }
        ov[col] = xr[j] + lv;
    }
    __syncthreads();
    for (int r = 0; r < NLIN; ++r) {
        float part = 0.f;
#pragma unroll
        for (int j = 0; j < 3; ++j) {
            const int col = tid + 256 * j;
            part = fmaf(ov[col], lin_w[r * DD + col], part);
        }
        for (int off = 32; off > 0; off >>= 1) part += __shfl_down(part, off);
        if (lane == 0) red[r][wid] = part;
    }
    __syncthreads();
    if (tid < NLIN)
        out[(size_t)P * NLIN + tid] = red[tid][0] + red[tid][1] + red[tid][2] + red[tid][3] + lin_b[tid];
}

// ---------------------------------------------------------------- launch
extern "C" void kernel_launch(void* const* d_in, const int* in_sizes, int n_in,
                              void* d_out, int out_size, void* d_ws, size_t ws_size,
                              hipStream_t stream) {
    (void)in_sizes; (void)n_in; (void)out_size; (void)ws_size;
    const float* seq   = (const float*)d_in[0];
    const int*   valid = (const int*)d_in[1];
    const float* wih_f = (const float*)d_in[2];
    const float* whh_f = (const float*)d_in[3];
    const float* bih_f = (const float*)d_in[4];
    const float* bhh_f = (const float*)d_in[5];
    const float* wih_b = (const float*)d_in[6];
    const float* whh_b = (const float*)d_in[7];
    const float* bih_b = (const float*)d_in[8];
    const float* bhh_b = (const float*)d_in[9];
    const float* lin_w = (const float*)d_in[10];
    const float* lin_b = (const float*)d_in[11];
    float* out = (float*)d_out;

    float* x    = (float*)d_ws;                       // 786432 f
    float* proj = x + (size_t)NPOS * DD;              // 12582912 f
    float* hout = proj + (size_t)NPOS * PROJ_N;       // 3145728 f

    zero_f4<<<(NPOS * DD / 4 + 255) / 256, 256, 0, stream>>>((float4*)x, NPOS * DD / 4);
    scatter_kernel<<<32, 256, 0, stream>>>(seq, valid, x);
    proj_gemm<<<dim3(PROJ_N / 64, NPOS / 64), 256, 0, stream>>>(
        x, wih_f, wih_b, bih_f, bhh_f, bih_b, bhh_b, proj);
    lstm_rec<<<512, 384, 0, stream>>>(proj, whh_f, whh_b, hout);
    attn_out_kernel<<<NPOS, 256, 0, stream>>>(x, hout, lin_w, lin_b, out);
}

// Round 2
// 837.970 us; speedup vs baseline: 2.6325x; 2.6325x over previous
//
#include <hip/hip_runtime.h>
#include <math.h>

#define LL 256
#define DD 768
#define HH 384
#define G4 1536
#define NWIN 4
#define NLIN 9
#define NPOS 1024        // B*L
#define PROJ_N 12288     // 8 chains * 1536
#define WHH_TOT 4718592  // 8*1536*384
#define WHH_HALF 2359296 // 4*1536*384

typedef __attribute__((ext_vector_type(8))) short short8;
typedef __attribute__((ext_vector_type(4))) short short4v;
typedef __attribute__((ext_vector_type(16))) float f32x16;

static __device__ __forceinline__ float bf2f(unsigned short u) {
    union { unsigned int i; float f; } v; v.i = ((unsigned int)u) << 16; return v.f;
}
static __device__ __forceinline__ unsigned short f2bf(float f) {
    unsigned int u = __float_as_uint(f);
    u += 0x7fff + ((u >> 16) & 1);   // round-to-nearest-even
    return (unsigned short)(u >> 16);
}

// ---------------------------------------------------------------- zero
__global__ void zero_f4(float4* __restrict__ p, int n4) {
    int i = blockIdx.x * blockDim.x + threadIdx.x;
    if (i < n4) p[i] = make_float4(0.f, 0.f, 0.f, 0.f);
}

// ---------------------------------------------------------------- scatter
__global__ void scatter_kernel(const float* __restrict__ seq,
                               const int* __restrict__ valid,
                               float* __restrict__ x) {
    const int b = blockIdx.x >> 3;
    const int chunk = blockIdx.x & 7;
    const int tid = threadIdx.x;
    __shared__ int vbuf[LL];
    __shared__ int dest[LL];
    vbuf[tid] = valid[b * LL + tid];
    __syncthreads();
    if (tid == 0) {
        int c = 0;
        for (int l = 0; l < LL; ++l) dest[l] = vbuf[l] ? c++ : -1;
    }
    __syncthreads();
    for (int l = chunk * 32; l < chunk * 32 + 32; ++l) {
        const int d = dest[l];
        if (d >= 0) {
            const float4* src = (const float4*)(seq + (size_t)(b * LL + l) * DD);
            float4* dst = (float4*)(x + (size_t)(b * LL + d) * DD);
            for (int j = tid; j < DD / 4; j += blockDim.x) dst[j] = src[j];
        }
    }
}

// ---------------------------------------------------------------- W_hh fp32 -> bf16
__global__ __launch_bounds__(256) void cast_w(const float* __restrict__ wf,
                                              const float* __restrict__ wb,
                                              unsigned short* __restrict__ out) {
    const int i = (blockIdx.x * 256 + threadIdx.x) * 4;
    const float4 v = (i < WHH_HALF) ? *(const float4*)(wf + i)
                                    : *(const float4*)(wb + (i - WHH_HALF));
    short4v pv;
    pv.x = (short)f2bf(v.x); pv.y = (short)f2bf(v.y);
    pv.z = (short)f2bf(v.z); pv.w = (short)f2bf(v.w);
    *(short4v*)(out + i) = pv;
}

// ---------------------------------------------------------------- proj GEMM (fp32 compute, bf16 out)
__global__ __launch_bounds__(256) void proj_gemm(
        const float* __restrict__ x,
        const float* __restrict__ wih_f, const float* __restrict__ wih_b,
        const float* __restrict__ bih_f, const float* __restrict__ bhh_f,
        const float* __restrict__ bih_b, const float* __restrict__ bhh_b,
        unsigned short* __restrict__ proj) {
    const int n0 = blockIdx.x * 64;
    const int m0 = blockIdx.y * 64;
    const int tid = threadIdx.x;
    const int tx = tid & 15, ty = tid >> 4;
    __shared__ __align__(16) float As[16][68];
    __shared__ __align__(16) float Bs[16][68];
    const int lr = tid >> 2;
    const int lk = (tid & 3) * 4;
    const int nrow = n0 + lr;
    const int chain = nrow / G4;
    const int rr = nrow % G4;
    const int dirb = chain >> 2, wib = chain & 3;
    const float* wrow = (dirb ? wih_b : wih_f) + (size_t)(wib * G4 + rr) * DD;
    const float* arow = x + (size_t)(m0 + lr) * DD;
    float acc[4][4] = {};
    for (int k0 = 0; k0 < DD; k0 += 16) {
        const float4 av = *(const float4*)(arow + k0 + lk);
        const float4 bv = *(const float4*)(wrow + k0 + lk);
        As[lk + 0][lr] = av.x; As[lk + 1][lr] = av.y;
        As[lk + 2][lr] = av.z; As[lk + 3][lr] = av.w;
        Bs[lk + 0][lr] = bv.x; Bs[lk + 1][lr] = bv.y;
        Bs[lk + 2][lr] = bv.z; Bs[lk + 3][lr] = bv.w;
        __syncthreads();
#pragma unroll
        for (int k = 0; k < 16; ++k) {
            const float4 a = *(const float4*)&As[k][ty * 4];
            const float4 bq = *(const float4*)&Bs[k][tx * 4];
            acc[0][0] = fmaf(a.x, bq.x, acc[0][0]); acc[0][1] = fmaf(a.x, bq.y, acc[0][1]);
            acc[0][2] = fmaf(a.x, bq.z, acc[0][2]); acc[0][3] = fmaf(a.x, bq.w, acc[0][3]);
            acc[1][0] = fmaf(a.y, bq.x, acc[1][0]); acc[1][1] = fmaf(a.y, bq.y, acc[1][1]);
            acc[1][2] = fmaf(a.y, bq.z, acc[1][2]); acc[1][3] = fmaf(a.y, bq.w, acc[1][3]);
            acc[2][0] = fmaf(a.z, bq.x, acc[2][0]); acc[2][1] = fmaf(a.z, bq.y, acc[2][1]);
            acc[2][2] = fmaf(a.z, bq.z, acc[2][2]); acc[2][3] = fmaf(a.z, bq.w, acc[2][3]);
            acc[3][0] = fmaf(a.w, bq.x, acc[3][0]); acc[3][1] = fmaf(a.w, bq.y, acc[3][1]);
            acc[3][2] = fmaf(a.w, bq.z, acc[3][2]); acc[3][3] = fmaf(a.w, bq.w, acc[3][3]);
        }
        __syncthreads();
    }
    const int colbase = n0 + tx * 4;
    const int chain_c = colbase / G4;
    const int rbase = colbase % G4;
    const int dc = chain_c >> 2, wc = chain_c & 3;
    const float* bi = dc ? bih_b : bih_f;
    const float* bh = dc ? bhh_b : bhh_f;
    float bias[4];
#pragma unroll
    for (int j = 0; j < 4; ++j)
        bias[j] = bi[wc * G4 + rbase + j] + bh[wc * G4 + rbase + j];
#pragma unroll
    for (int i = 0; i < 4; ++i) {
        const int row = m0 + ty * 4 + i;
        short4v pv;
        pv.x = (short)f2bf(acc[i][0] + bias[0]);
        pv.y = (short)f2bf(acc[i][1] + bias[1]);
        pv.z = (short)f2bf(acc[i][2] + bias[2]);
        pv.w = (short)f2bf(acc[i][3] + bias[3]);
        *(short4v*)&proj[(size_t)row * PROJ_N + colbase] = pv;
    }
}

// ---------------------------------------------------------------- LSTM step (MFMA)
// One launch advances ALL positions of all active chains by one step.
// Block: 256 thr = 4 waves; wave wv owns units [u0+wv*32, +32), all 4 gates,
// 32 positions. gates = Hin @ W^T via v_mfma_f32_32x32x16_bf16; epilogue does
// the cell update in-register (i,f,g,o live in 4 accumulators, same (lane,reg)
// -> same (pos,unit)). Hin/Hout ping-pong across launches (no intra-grid race).
__global__ __launch_bounds__(256) void lstm_step(
        const unsigned short* __restrict__ Wbf,
        const unsigned short* __restrict__ proj,
        const unsigned short* __restrict__ Hin,
        unsigned short* __restrict__ Hout,
        float* __restrict__ Cst,
        int s, int wi_min) {
    const int nwi = 4 - wi_min;
    const int cIdx = blockIdx.x / 96;
    const int rem  = blockIdx.x % 96;
    const int m0 = (rem & 31) * 32;
    const int u0 = (rem >> 5) * 128;
    const int dir = (cIdx >= nwi) ? 1 : 0;
    const int wi = wi_min + (dir ? (cIdx - nwi) : cIdx);
    const int chain = dir * 4 + wi;
    const int w = 3 + 2 * wi;
    const int half = wi + 1;
    const int t = dir ? (w - 1 - s) : s;

    const int lane = threadIdx.x & 63;
    const int wv = threadIdx.x >> 6;
    const int colid = lane & 31;   // A row (pos) / B col (unit)
    const int hq = lane >> 5;      // k-half selector
    const int uu = u0 + wv * 32 + colid;

    const unsigned short* Hc = Hin + (size_t)chain * (NPOS * HH);
    const unsigned short* Wc = Wbf + (size_t)chain * (G4 * HH);

    const unsigned short* aP  = Hc + (size_t)(m0 + colid) * HH + hq * 8;
    const unsigned short* b0P = Wc + (size_t)(0 * HH + uu) * HH + hq * 8;
    const unsigned short* b1P = Wc + (size_t)(1 * HH + uu) * HH + hq * 8;
    const unsigned short* b2P = Wc + (size_t)(2 * HH + uu) * HH + hq * 8;
    const unsigned short* b3P = Wc + (size_t)(3 * HH + uu) * HH + hq * 8;

    f32x16 acc0 = {}, acc1 = {}, acc2 = {}, acc3 = {};
#pragma unroll 6
    for (int ks = 0; ks < 24; ++ks) {
        const short8 av  = *(const short8*)(aP  + ks * 16);
        const short8 bv0 = *(const short8*)(b0P + ks * 16);
        const short8 bv1 = *(const short8*)(b1P + ks * 16);
        const short8 bv2 = *(const short8*)(b2P + ks * 16);
        const short8 bv3 = *(const short8*)(b3P + ks * 16);
        acc0 = __builtin_amdgcn_mfma_f32_32x32x16_bf16(av, bv0, acc0, 0, 0, 0);
        acc1 = __builtin_amdgcn_mfma_f32_32x32x16_bf16(av, bv1, acc1, 0, 0, 0);
        acc2 = __builtin_amdgcn_mfma_f32_32x32x16_bf16(av, bv2, acc2, 0, 0, 0);
        acc3 = __builtin_amdgcn_mfma_f32_32x32x16_bf16(av, bv3, acc3, 0, 0, 0);
    }

    const int b = m0 >> 8;
    const int l0 = m0 & 255;
#pragma unroll
    for (int r = 0; r < 16; ++r) {
        const int row = (r & 3) + 8 * (r >> 2) + 4 * hq;  // C/D layout (m74/m101)
        const int src = l0 + row + t - half;
        const bool valid = (src >= 0) && (src < LL);
        const int srcc = src < 0 ? 0 : (src > LL - 1 ? LL - 1 : src);
        const size_t pb = (size_t)(b * LL + srcc) * PROJ_N + chain * G4 + uu;
        const size_t hidx = (size_t)chain * (NPOS * HH) + (size_t)(m0 + row) * HH + uu;
        if (valid) {
            const float gi = acc0[r] + bf2f(proj[pb]);
            const float gf = acc1[r] + bf2f(proj[pb + HH]);
            const float gg = acc2[r] + bf2f(proj[pb + 2 * HH]);
            const float go = acc3[r] + bf2f(proj[pb + 3 * HH]);
            const float iv = 1.f / (1.f + __expf(-gi));
            const float fv = 1.f / (1.f + __expf(-gf));
            const float gv = tanhf(gg);
            const float ov = 1.f / (1.f + __expf(-go));
            const float cn = fv * Cst[hidx] + iv * gv;
            Cst[hidx] = cn;
            Hout[hidx] = f2bf(ov * tanhf(cn));
        } else {
            Hout[hidx] = Hin[hidx];
        }
    }
}

// ---------------------------------------------------------------- attention + linear head
__global__ __launch_bounds__(256) void attn_out_kernel(
        const float* __restrict__ x, const unsigned short* __restrict__ hout,
        const float* __restrict__ lin_w, const float* __restrict__ lin_b,
        float* __restrict__ out) {
    const int P = blockIdx.x;
    const int tid = threadIdx.x;
    const int lane = tid & 63, wid = tid >> 6;
    __shared__ float sc[NWIN][4];
    __shared__ float attn_s[NWIN];
    __shared__ float ov[DD];
    __shared__ float red[NLIN][4];
    const float inv_sqrt_d = 0.03608439182435161f;

    float xr[3];
#pragma unroll
    for (int j = 0; j < 3; ++j) xr[j] = x[(size_t)P * DD + tid + 256 * j];

#pragma unroll
    for (int wi = 0; wi < NWIN; ++wi) {
        float part = 0.f;
#pragma unroll
        for (int j = 0; j < 3; ++j) {
            const int col = tid + 256 * j;
            const float m = (col < HH)
                ? bf2f(hout[(size_t)(wi * NPOS + P) * HH + col])
                : bf2f(hout[(size_t)((4 + wi) * NPOS + P) * HH + col - HH]);
            part = fmaf(xr[j], m, part);
        }
        for (int off = 32; off > 0; off >>= 1) part += __shfl_down(part, off);
        if (lane == 0) sc[wi][wid] = part;
    }
    __syncthreads();
    if (tid == 0) {
        float s[NWIN], mx = -1e30f;
        for (int wi = 0; wi < NWIN; ++wi) {
            s[wi] = (sc[wi][0] + sc[wi][1] + sc[wi][2] + sc[wi][3]) * inv_sqrt_d;
            mx = fmaxf(mx, s[wi]);
        }
        float denom = 0.f;
        for (int wi = 0; wi < NWIN; ++wi) { s[wi] = __expf(s[wi] - mx); denom += s[wi]; }
        for (int wi = 0; wi < NWIN; ++wi) attn_s[wi] = s[wi] / denom;
    }
    __syncthreads();
#pragma unroll
    for (int j = 0; j < 3; ++j) {
        const int col = tid + 256 * j;
        float lv = 0.f;
#pragma unroll
        for (int wi = 0; wi < NWIN; ++wi) {
            const float m = (col < HH)
                ? bf2f(hout[(size_t)(wi * NPOS + P) * HH + col])
                : bf2f(hout[(size_t)((4 + wi) * NPOS + P) * HH + col - HH]);
            lv = fmaf(attn_s[wi], m, lv);
        }
        ov[col] = xr[j] + lv;
    }
    __syncthreads();
    for (int r = 0; r < NLIN; ++r) {
        float part = 0.f;
#pragma unroll
        for (int j = 0; j < 3; ++j) {
            const int col = tid + 256 * j;
            part = fmaf(ov[col], lin_w[r * DD + col], part);
        }
        for (int off = 32; off > 0; off >>= 1) part += __shfl_down(part, off);
        if (lane == 0) red[r][wid] = part;
    }
    __syncthreads();
    if (tid < NLIN)
        out[(size_t)P * NLIN + tid] = red[tid][0] + red[tid][1] + red[tid][2] + red[tid][3] + lin_b[tid];
}

// ---------------------------------------------------------------- launch
extern "C" void kernel_launch(void* const* d_in, const int* in_sizes, int n_in,
                              void* d_out, int out_size, void* d_ws, size_t ws_size,
                              hipStream_t stream) {
    (void)in_sizes; (void)n_in; (void)out_size; (void)ws_size;
    const float* seq   = (const float*)d_in[0];
    const int*   valid = (const int*)d_in[1];
    const float* wih_f = (const float*)d_in[2];
    const float* whh_f = (const float*)d_in[3];
    const float* bih_f = (const float*)d_in[4];
    const float* bhh_f = (const float*)d_in[5];
    const float* wih_b = (const float*)d_in[6];
    const float* whh_b = (const float*)d_in[7];
    const float* bih_b = (const float*)d_in[8];
    const float* bhh_b = (const float*)d_in[9];
    const float* lin_w = (const float*)d_in[10];
    const float* lin_b = (const float*)d_in[11];
    float* out = (float*)d_out;

    // workspace layout (63 MB total)
    float*          x    = (float*)d_ws;                        // 1024*768 f32
    unsigned short* proj = (unsigned short*)(x + NPOS * DD);    // 1024*12288 bf16
    unsigned short* wbf  = proj + (size_t)NPOS * PROJ_N;        // 8*1536*384 bf16
    unsigned short* h0   = wbf + WHH_TOT;                       // 8*1024*384 bf16
    unsigned short* h1   = h0 + (size_t)8 * NPOS * HH;          // 8*1024*384 bf16
    float*          cst  = (float*)(h1 + (size_t)8 * NPOS * HH); // 8*1024*384 f32

    zero_f4<<<(NPOS * DD / 4 + 255) / 256, 256, 0, stream>>>((float4*)x, NPOS * DD / 4);
    zero_f4<<<(8 * NPOS * HH / 8 + 255) / 256, 256, 0, stream>>>((float4*)h0, 8 * NPOS * HH / 8);
    zero_f4<<<(8 * NPOS * HH / 4 + 255) / 256, 256, 0, stream>>>((float4*)cst, 8 * NPOS * HH / 4);
    scatter_kernel<<<32, 256, 0, stream>>>(seq, valid, x);
    cast_w<<<WHH_TOT / 4 / 256, 256, 0, stream>>>(whh_f, whh_b, wbf);
    proj_gemm<<<dim3(PROJ_N / 64, NPOS / 64), 256, 0, stream>>>(
        x, wih_f, wih_b, bih_f, bhh_f, bih_b, bhh_b, proj);
    for (int s = 0; s < 9; ++s) {
        const int wi_min = s <= 2 ? 0 : (s <= 4 ? 1 : (s <= 6 ? 2 : 3));
        const int nAct = 2 * (4 - wi_min);
        const unsigned short* hin = (s & 1) ? h1 : h0;
        unsigned short*      hou = (s & 1) ? h0 : h1;
        lstm_step<<<nAct * 96, 256, 0, stream>>>(wbf, proj, hin, hou, cst, s, wi_min);
    }
    attn_out_kernel<<<NPOS, 256, 0, stream>>>(x, h1, lin_w, lin_b, out);
}

// Round 3
// 498.432 us; speedup vs baseline: 4.4257x; 1.6812x over previous
//
#include <hip/hip_runtime.h>
#include <math.h>

#define LL 256
#define DD 768
#define HH 384
#define G4 1536
#define NWIN 4
#define NLIN 9
#define NPOS 1024        // B*L
#define PROJ_N 12288     // 8 chains * 1536

typedef __attribute__((ext_vector_type(8))) short short8;
typedef __attribute__((ext_vector_type(16))) float f32x16;

static __device__ __forceinline__ float bf2f(unsigned short u) {
    union { unsigned int i; float f; } v; v.i = ((unsigned int)u) << 16; return v.f;
}
static __device__ __forceinline__ unsigned short f2bf(float f) {
    unsigned int u = __float_as_uint(f);
    u += 0x7fff + ((u >> 16) & 1);   // round-to-nearest-even
    return (unsigned short)(u >> 16);
}

// ---------------------------------------------------------------- zero
__global__ void zero_f4(float4* __restrict__ p, int n4) {
    int i = blockIdx.x * blockDim.x + threadIdx.x;
    if (i < n4) p[i] = make_float4(0.f, 0.f, 0.f, 0.f);
}

// ---------------------------------------------------------------- scatter
// x[b, dest[l], :] = seq[b, l, :] ; also writes bf16 MFMA-A-fragment layout:
// xfrag[pt][ks][lane][8], lane = (pos&31) + 32*khalf, k = ks*16 + khalf*8 + j
__global__ void scatter_kernel(const float* __restrict__ seq,
                               const int* __restrict__ valid,
                               float* __restrict__ x,
                               unsigned short* __restrict__ xfrag) {
    const int b = blockIdx.x >> 3;
    const int chunk = blockIdx.x & 7;
    const int tid = threadIdx.x;
    __shared__ int vbuf[LL];
    __shared__ int dest[LL];
    vbuf[tid] = valid[b * LL + tid];
    __syncthreads();
    if (tid == 0) {
        int c = 0;
        for (int l = 0; l < LL; ++l) dest[l] = vbuf[l] ? c++ : -1;
    }
    __syncthreads();
    for (int l = chunk * 32; l < chunk * 32 + 32; ++l) {
        const int d = dest[l];
        if (d >= 0) {
            const float* src = seq + (size_t)(b * LL + l) * DD;
            float* dst = x + (size_t)(b * LL + d) * DD;
            for (int j = tid; j < DD / 4; j += 256)
                ((float4*)dst)[j] = ((const float4*)src)[j];
            const int pos = b * LL + d;
            const int pt = pos >> 5, pl = pos & 31;
            for (int j = tid; j < DD / 8; j += 256) {
                const float4 v0 = ((const float4*)src)[2 * j];
                const float4 v1 = ((const float4*)src)[2 * j + 1];
                short8 pv;
                pv[0] = (short)f2bf(v0.x); pv[1] = (short)f2bf(v0.y);
                pv[2] = (short)f2bf(v0.z); pv[3] = (short)f2bf(v0.w);
                pv[4] = (short)f2bf(v1.x); pv[5] = (short)f2bf(v1.y);
                pv[6] = (short)f2bf(v1.z); pv[7] = (short)f2bf(v1.w);
                *(short8*)(xfrag + ((size_t)(pt * 48 + (j >> 1)) * 512 + (pl + 32 * (j & 1)) * 8)) = pv;
            }
        }
    }
}

// ---------------------------------------------------------------- cast weights -> B-fragment layout
// Virtual rows n in [0, 12288): chain = n/1536 (dir*4+wi), src row = n%1536.
// dst[tile][ks][lane][8]: lane = (n&31) + 32*khalf, value = W[n][ks*16+khalf*8+j]
__global__ __launch_bounds__(256) void cast_frag(
        const float* __restrict__ srcF, const float* __restrict__ srcB,
        unsigned short* __restrict__ dst, int K) {
    __shared__ unsigned short lds[32 * 768];
    const int tid = threadIdx.x;
    const int vrow0 = blockIdx.x * 32;
    const int chain = vrow0 / G4;
    const int dir = chain >> 2, wi = chain & 3;
    const float* src = (dir ? srcB : srcF) + (size_t)(wi * G4 + (vrow0 % G4)) * K;
    const int total = 32 * K;
    for (int i = tid * 4; i < total; i += 1024) {
        const float4 v = *(const float4*)(src + i);
        lds[i + 0] = f2bf(v.x); lds[i + 1] = f2bf(v.y);
        lds[i + 2] = f2bf(v.z); lds[i + 3] = f2bf(v.w);
    }
    __syncthreads();
    const int nks = K >> 4;
    for (int slot = tid; slot < nks * 64; slot += 256) {
        const int ks = slot >> 6;
        const int lane = slot & 63;
        const int row = lane & 31;
        const int kb = ks * 16 + (lane >> 5) * 8;
        const short8 v = *(const short8*)&lds[row * K + kb];
        *(short8*)(dst + ((size_t)blockIdx.x * nks + ks) * 512 + lane * 8) = v;
    }
}

// ---------------------------------------------------------------- combined bias
__global__ void bias_kernel(const float* __restrict__ bihf, const float* __restrict__ bhhf,
                            const float* __restrict__ bihb, const float* __restrict__ bhhb,
                            float* __restrict__ bias) {
    const int n = blockIdx.x * 256 + threadIdx.x;
    if (n >= PROJ_N) return;
    const int chain = n / G4, r = n % G4;
    const int dir = chain >> 2, wi = chain & 3;
    bias[n] = (dir ? bihb : bihf)[wi * G4 + r] + (dir ? bhhb : bhhf)[wi * G4 + r];
}

// ---------------------------------------------------------------- proj GEMM (MFMA, frag-direct)
// Wave computes 64 pos x 128 n. Grid: 16 m-groups * 96 n-groups = 1536 waves = 384 blocks.
__global__ __launch_bounds__(256) void proj_mfma(
        const unsigned short* __restrict__ xf,
        const unsigned short* __restrict__ wf,
        const float* __restrict__ bias,
        unsigned short* __restrict__ proj) {
    const int wv = threadIdx.x >> 6;
    const int lane = threadIdx.x & 63;
    const int colid = lane & 31, hq = lane >> 5;
    const int tile = blockIdx.x * 4 + wv;
    const int mt = tile / 96, nt = tile % 96;
    const unsigned short* aP0 = xf + (size_t)(mt * 2 * 48) * 512 + lane * 8;
    const unsigned short* aP1 = aP0 + 48 * 512;
    const unsigned short* bP = wf + (size_t)(nt * 4 * 48) * 512 + lane * 8;

    f32x16 acc[2][4] = {};
#pragma unroll 2
    for (int ks = 0; ks < 48; ++ks) {
        const short8 a0 = *(const short8*)(aP0 + ks * 512);
        const short8 a1 = *(const short8*)(aP1 + ks * 512);
#pragma unroll
        for (int jj = 0; jj < 4; ++jj) {
            const short8 bv = *(const short8*)(bP + (size_t)(jj * 48 + ks) * 512);
            acc[0][jj] = __builtin_amdgcn_mfma_f32_32x32x16_bf16(a0, bv, acc[0][jj], 0, 0, 0);
            acc[1][jj] = __builtin_amdgcn_mfma_f32_32x32x16_bf16(a1, bv, acc[1][jj], 0, 0, 0);
        }
    }
    const int n_base = nt * 128 + colid;
#pragma unroll
    for (int jj = 0; jj < 4; ++jj) {
        const float bv = bias[n_base + jj * 32];
#pragma unroll
        for (int i = 0; i < 2; ++i) {
#pragma unroll
            for (int r = 0; r < 16; ++r) {
                const int row = (r & 3) + 8 * (r >> 2) + 4 * hq;
                const int pos = mt * 64 + i * 32 + row;
                proj[(size_t)pos * PROJ_N + n_base + jj * 32] = f2bf(acc[i][jj][r] + bv);
            }
        }
    }
}

// ---------------------------------------------------------------- LSTM step (MFMA, frag layouts)
// H stored in A-fragment layout: Hfrag[chain][pt(32)][ks(24)][lane][8].
// W_hh in B-fragment layout: Wfrag[chain*48 + g*12 + utile][ks(24)][lane][8].
__global__ __launch_bounds__(256) void lstm_step(
        const unsigned short* __restrict__ Wf,
        const unsigned short* __restrict__ proj,
        const unsigned short* __restrict__ Hin,
        unsigned short* __restrict__ Hout,
        float* __restrict__ Cst,
        int s, int wi_min) {
    const int nwi = 4 - wi_min;
    const int cIdx = blockIdx.x / 96;
    const int rem  = blockIdx.x % 96;
    const int pt = rem & 31;
    const int u0 = (rem >> 5) * 128;
    const int dir = (cIdx >= nwi) ? 1 : 0;
    const int wi = wi_min + (dir ? (cIdx - nwi) : cIdx);
    const int chain = dir * 4 + wi;
    const int w = 3 + 2 * wi;
    const int half = wi + 1;
    const int t = dir ? (w - 1 - s) : s;

    const int lane = threadIdx.x & 63;
    const int wv = threadIdx.x >> 6;
    const int colid = lane & 31;
    const int hq = lane >> 5;
    const int uu = u0 + wv * 32 + colid;
    const int m0 = pt * 32;

    const unsigned short* aP = Hin + (size_t)chain * (NPOS * HH) + (size_t)(pt * 24) * 512 + lane * 8;
    const int ut = (u0 >> 5) + wv;
    const unsigned short* bP = Wf + (size_t)((chain * 48 + ut) * 24) * 512 + lane * 8;
    const unsigned short* b1P = bP + (size_t)(12 * 24) * 512;
    const unsigned short* b2P = bP + (size_t)(24 * 24) * 512;
    const unsigned short* b3P = bP + (size_t)(36 * 24) * 512;

    f32x16 acc0 = {}, acc1 = {}, acc2 = {}, acc3 = {};
#pragma unroll 4
    for (int ks = 0; ks < 24; ++ks) {
        const short8 av  = *(const short8*)(aP  + ks * 512);
        const short8 bv0 = *(const short8*)(bP  + ks * 512);
        const short8 bv1 = *(const short8*)(b1P + ks * 512);
        const short8 bv2 = *(const short8*)(b2P + ks * 512);
        const short8 bv3 = *(const short8*)(b3P + ks * 512);
        acc0 = __builtin_amdgcn_mfma_f32_32x32x16_bf16(av, bv0, acc0, 0, 0, 0);
        acc1 = __builtin_amdgcn_mfma_f32_32x32x16_bf16(av, bv1, acc1, 0, 0, 0);
        acc2 = __builtin_amdgcn_mfma_f32_32x32x16_bf16(av, bv2, acc2, 0, 0, 0);
        acc3 = __builtin_amdgcn_mfma_f32_32x32x16_bf16(av, bv3, acc3, 0, 0, 0);
    }

    const int b = m0 >> 8;
    const int l0 = m0 & 255;
    const int ksp = uu >> 4, khp = (uu >> 3) & 1, jp = uu & 7;
    const size_t hbase = (size_t)chain * (NPOS * HH) + (size_t)(pt * 24 + ksp) * 512 + khp * 256 + jp;
#pragma unroll
    for (int r = 0; r < 16; ++r) {
        const int row = (r & 3) + 8 * (r >> 2) + 4 * hq;  // C/D layout
        const int src = l0 + row + t - half;
        const bool valid = (src >= 0) && (src < LL);
        const int srcc = src < 0 ? 0 : (src > LL - 1 ? LL - 1 : src);
        const size_t pb = (size_t)(b * LL + srcc) * PROJ_N + chain * G4 + uu;
        const size_t hidx = hbase + row * 8;
        const size_t cidx = (size_t)chain * (NPOS * HH) + (size_t)(m0 + row) * HH + uu;
        if (valid) {
            const float gi = acc0[r] + bf2f(proj[pb]);
            const float gf = acc1[r] + bf2f(proj[pb + HH]);
            const float gg = acc2[r] + bf2f(proj[pb + 2 * HH]);
            const float go = acc3[r] + bf2f(proj[pb + 3 * HH]);
            const float iv = 1.f / (1.f + __expf(-gi));
            const float fv = 1.f / (1.f + __expf(-gf));
            const float gv = tanhf(gg);
            const float ov = 1.f / (1.f + __expf(-go));
            const float cn = fv * Cst[cidx] + iv * gv;
            Cst[cidx] = cn;
            Hout[hidx] = f2bf(ov * tanhf(cn));
        } else {
            Hout[hidx] = Hin[hidx];
        }
    }
}

// ---------------------------------------------------------------- attention + linear head
static __device__ __forceinline__ float hfrag_get(const unsigned short* __restrict__ h,
                                                  int chain, int P, int c) {
    const size_t idx = (size_t)chain * (NPOS * HH)
        + (size_t)((P >> 5) * 24 + (c >> 4)) * 512
        + ((P & 31) + 32 * ((c >> 3) & 1)) * 8 + (c & 7);
    return bf2f(h[idx]);
}

__global__ __launch_bounds__(256) void attn_out_kernel(
        const float* __restrict__ x, const unsigned short* __restrict__ hout,
        const float* __restrict__ lin_w, const float* __restrict__ lin_b,
        float* __restrict__ out) {
    const int P = blockIdx.x;
    const int tid = threadIdx.x;
    const int lane = tid & 63, wid = tid >> 6;
    __shared__ float sc[NWIN][4];
    __shared__ float attn_s[NWIN];
    __shared__ float ov[DD];
    __shared__ float red[NLIN][4];
    const float inv_sqrt_d = 0.03608439182435161f;

    float xr[3];
#pragma unroll
    for (int j = 0; j < 3; ++j) xr[j] = x[(size_t)P * DD + tid + 256 * j];

#pragma unroll
    for (int wi = 0; wi < NWIN; ++wi) {
        float part = 0.f;
#pragma unroll
        for (int j = 0; j < 3; ++j) {
            const int col = tid + 256 * j;
            const float m = (col < HH) ? hfrag_get(hout, wi, P, col)
                                       : hfrag_get(hout, 4 + wi, P, col - HH);
            part = fmaf(xr[j], m, part);
        }
        for (int off = 32; off > 0; off >>= 1) part += __shfl_down(part, off);
        if (lane == 0) sc[wi][wid] = part;
    }
    __syncthreads();
    if (tid == 0) {
        float s[NWIN], mx = -1e30f;
        for (int wi = 0; wi < NWIN; ++wi) {
            s[wi] = (sc[wi][0] + sc[wi][1] + sc[wi][2] + sc[wi][3]) * inv_sqrt_d;
            mx = fmaxf(mx, s[wi]);
        }
        float denom = 0.f;
        for (int wi = 0; wi < NWIN; ++wi) { s[wi] = __expf(s[wi] - mx); denom += s[wi]; }
        for (int wi = 0; wi < NWIN; ++wi) attn_s[wi] = s[wi] / denom;
    }
    __syncthreads();
#pragma unroll
    for (int j = 0; j < 3; ++j) {
        const int col = tid + 256 * j;
        float lv = 0.f;
#pragma unroll
        for (int wi = 0; wi < NWIN; ++wi) {
            const float m = (col < HH) ? hfrag_get(hout, wi, P, col)
                                       : hfrag_get(hout, 4 + wi, P, col - HH);
            lv = fmaf(attn_s[wi], m, lv);
        }
        ov[col] = xr[j] + lv;
    }
    __syncthreads();
    for (int r = 0; r < NLIN; ++r) {
        float part = 0.f;
#pragma unroll
        for (int j = 0; j < 3; ++j) {
            const int col = tid + 256 * j;
            part = fmaf(ov[col], lin_w[r * DD + col], part);
        }
        for (int off = 32; off > 0; off >>= 1) part += __shfl_down(part, off);
        if (lane == 0) red[r][wid] = part;
    }
    __syncthreads();
    if (tid < NLIN)
        out[(size_t)P * NLIN + tid] = red[tid][0] + red[tid][1] + red[tid][2] + red[tid][3] + lin_b[tid];
}

// ---------------------------------------------------------------- launch
extern "C" void kernel_launch(void* const* d_in, const int* in_sizes, int n_in,
                              void* d_out, int out_size, void* d_ws, size_t ws_size,
                              hipStream_t stream) {
    (void)in_sizes; (void)n_in; (void)out_size; (void)ws_size;
    const float* seq   = (const float*)d_in[0];
    const int*   valid = (const int*)d_in[1];
    const float* wih_f = (const float*)d_in[2];
    const float* whh_f = (const float*)d_in[3];
    const float* bih_f = (const float*)d_in[4];
    const float* bhh_f = (const float*)d_in[5];
    const float* wih_b = (const float*)d_in[6];
    const float* whh_b = (const float*)d_in[7];
    const float* bih_b = (const float*)d_in[8];
    const float* bhh_b = (const float*)d_in[9];
    const float* lin_w = (const float*)d_in[10];
    const float* lin_b = (const float*)d_in[11];
    float* out = (float*)d_out;

    // workspace layout (~68.5 MB); cst aliases wfih (dead after proj_mfma)
    float*          x     = (float*)d_ws;                          // 786432 f32
    unsigned short* xfrag = (unsigned short*)(x + NPOS * DD);      // 786432 bf16
    unsigned short* proj  = xfrag + (size_t)NPOS * DD;             // 12582912 bf16
    unsigned short* wfhh  = proj + (size_t)NPOS * PROJ_N;          // 4718592 bf16
    unsigned short* h0    = wfhh + (size_t)4718592;                // 3145728 bf16
    unsigned short* h1    = h0 + (size_t)8 * NPOS * HH;            // 3145728 bf16
    float*          bias  = (float*)(h1 + (size_t)8 * NPOS * HH);  // 12288 f32
    unsigned short* wfih  = (unsigned short*)(bias + PROJ_N);      // 9437184 bf16
    float*          cst   = (float*)wfih;                          // alias: 3145728 f32

    zero_f4<<<(196608 + 255) / 256, 256, 0, stream>>>((float4*)x, 196608);
    zero_f4<<<(98304 + 255) / 256, 256, 0, stream>>>((float4*)xfrag, 98304);
    zero_f4<<<(393216 + 255) / 256, 256, 0, stream>>>((float4*)h0, 393216);
    scatter_kernel<<<32, 256, 0, stream>>>(seq, valid, x, xfrag);
    cast_frag<<<384, 256, 0, stream>>>(wih_f, wih_b, wfih, DD);
    cast_frag<<<384, 256, 0, stream>>>(whh_f, whh_b, wfhh, HH);
    bias_kernel<<<48, 256, 0, stream>>>(bih_f, bhh_f, bih_b, bhh_b, bias);
    proj_mfma<<<384, 256, 0, stream>>>(xfrag, wfih, bias, proj);
    zero_f4<<<(786432 + 255) / 256, 256, 0, stream>>>((float4*)cst, 786432);  // after proj (alias)
    for (int s = 0; s < 9; ++s) {
        const int wi_min = s <= 2 ? 0 : (s <= 4 ? 1 : (s <= 6 ? 2 : 3));
        const int nAct = 2 * (4 - wi_min);
        const unsigned short* hin = (s & 1) ? h1 : h0;
        unsigned short*      hou = (s & 1) ? h0 : h1;
        lstm_step<<<nAct * 96, 256, 0, stream>>>(wfhh, proj, hin, hou, cst, s, wi_min);
    }
    attn_out_kernel<<<NPOS, 256, 0, stream>>>(x, h1, lin_w, lin_b, out);
}

// Round 4
// 474.592 us; speedup vs baseline: 4.6480x; 1.0502x over previous
//
#include <hip/hip_runtime.h>
#include <math.h>

#define LL 256
#define DD 768
#define HH 384
#define G4 1536
#define NWIN 4
#define NLIN 9
#define NPOS 1024        // B*L
#define PROJ_N 12288     // 8 chains * 1536

typedef __attribute__((ext_vector_type(8))) short short8;
typedef __attribute__((ext_vector_type(4))) short short4v;
typedef __attribute__((ext_vector_type(16))) float f32x16;

static __device__ __forceinline__ float bf2f(unsigned short u) {
    union { unsigned int i; float f; } v; v.i = ((unsigned int)u) << 16; return v.f;
}
static __device__ __forceinline__ unsigned short f2bf(float f) {
    unsigned int u = __float_as_uint(f);
    u += 0x7fff + ((u >> 16) & 1);   // round-to-nearest-even
    return (unsigned short)(u >> 16);
}

// ---------------------------------------------------------------- zero
__global__ void zero_f4(float4* __restrict__ p, int n4) {
    int i = blockIdx.x * blockDim.x + threadIdx.x;
    if (i < n4) p[i] = make_float4(0.f, 0.f, 0.f, 0.f);
}

// ---------------------------------------------------------------- scatter
// x[b, dest[l], :] = seq[b, l, :] ; also writes bf16 MFMA-A-fragment layout:
// xfrag[pt][ks][lane][8], lane = (pos&31) + 32*khalf, k = ks*16 + khalf*8 + j
__global__ void scatter_kernel(const float* __restrict__ seq,
                               const int* __restrict__ valid,
                               float* __restrict__ x,
                               unsigned short* __restrict__ xfrag) {
    const int b = blockIdx.x >> 5;
    const int chunk = blockIdx.x & 31;
    const int tid = threadIdx.x;
    __shared__ int vbuf[LL];
    __shared__ int dest[LL];
    vbuf[tid] = valid[b * LL + tid];
    __syncthreads();
    if (tid == 0) {
        int c = 0;
        for (int l = 0; l < LL; ++l) dest[l] = vbuf[l] ? c++ : -1;
    }
    __syncthreads();
    for (int l = chunk * 8; l < chunk * 8 + 8; ++l) {
        const int d = dest[l];
        if (d >= 0) {
            const float* src = seq + (size_t)(b * LL + l) * DD;
            float* dst = x + (size_t)(b * LL + d) * DD;
            for (int j = tid; j < DD / 4; j += 256)
                ((float4*)dst)[j] = ((const float4*)src)[j];
            const int pos = b * LL + d;
            const int pt = pos >> 5, pl = pos & 31;
            for (int j = tid; j < DD / 8; j += 256) {
                const float4 v0 = ((const float4*)src)[2 * j];
                const float4 v1 = ((const float4*)src)[2 * j + 1];
                short8 pv;
                pv[0] = (short)f2bf(v0.x); pv[1] = (short)f2bf(v0.y);
                pv[2] = (short)f2bf(v0.z); pv[3] = (short)f2bf(v0.w);
                pv[4] = (short)f2bf(v1.x); pv[5] = (short)f2bf(v1.y);
                pv[6] = (short)f2bf(v1.z); pv[7] = (short)f2bf(v1.w);
                *(short8*)(xfrag + ((size_t)(pt * 48 + (j >> 1)) * 512 + (pl + 32 * (j & 1)) * 8)) = pv;
            }
        }
    }
}

// ---------------------------------------------------------------- cast weights -> B-fragment layout
// Virtual rows n in [0, 12288): chain = n/1536 (dir*4+wi), src row = n%1536.
// dst[tile][ks][lane][8]: lane = (n&31) + 32*khalf, value = W[n][ks*16+khalf*8+j]
__global__ __launch_bounds__(256) void cast_frag(
        const float* __restrict__ srcF, const float* __restrict__ srcB,
        unsigned short* __restrict__ dst, int K) {
    __shared__ unsigned short lds[32 * 768];
    const int tid = threadIdx.x;
    const int vrow0 = blockIdx.x * 32;
    const int chain = vrow0 / G4;
    const int dir = chain >> 2, wi = chain & 3;
    const float* src = (dir ? srcB : srcF) + (size_t)(wi * G4 + (vrow0 % G4)) * K;
    const int total = 32 * K;
    for (int i = tid * 4; i < total; i += 1024) {
        const float4 v = *(const float4*)(src + i);
        lds[i + 0] = f2bf(v.x); lds[i + 1] = f2bf(v.y);
        lds[i + 2] = f2bf(v.z); lds[i + 3] = f2bf(v.w);
    }
    __syncthreads();
    const int nks = K >> 4;
    for (int slot = tid; slot < nks * 64; slot += 256) {
        const int ks = slot >> 6;
        const int lane = slot & 63;
        const int row = lane & 31;
        const int kb = ks * 16 + (lane >> 5) * 8;
        const short8 v = *(const short8*)&lds[row * K + kb];
        *(short8*)(dst + ((size_t)blockIdx.x * nks + ks) * 512 + lane * 8) = v;
    }
}

// ---------------------------------------------------------------- combined bias
__global__ void bias_kernel(const float* __restrict__ bihf, const float* __restrict__ bhhf,
                            const float* __restrict__ bihb, const float* __restrict__ bhhb,
                            float* __restrict__ bias) {
    const int n = blockIdx.x * 256 + threadIdx.x;
    if (n >= PROJ_N) return;
    const int chain = n / G4, r = n % G4;
    const int dir = chain >> 2, wi = chain & 3;
    bias[n] = (dir ? bihb : bihf)[wi * G4 + r] + (dir ? bhhb : bhhf)[wi * G4 + r];
}

// ---------------------------------------------------------------- proj GEMM (MFMA, frag-direct)
// Wave computes 32 pos x 64 n. 6144 wave-tiles -> 1536 blocks -> 6 waves/SIMD.
// Output layout: proj[pos][chain][u(384)][gate(4)]  (gate innermost, short4-loadable)
__global__ __launch_bounds__(256) void proj_mfma(
        const unsigned short* __restrict__ xf,
        const unsigned short* __restrict__ wf,
        const float* __restrict__ bias,
        unsigned short* __restrict__ proj) {
    const int wv = threadIdx.x >> 6;
    const int lane = threadIdx.x & 63;
    const int colid = lane & 31, hq = lane >> 5;
    const int tile = blockIdx.x * 4 + wv;   // 0..6143
    const int mt = tile / 192;              // 32-pos tile 0..31
    const int ng = tile % 192;              // 64-n group
    const unsigned short* aP = xf + (size_t)(mt * 48) * 512 + lane * 8;
    const unsigned short* bP = wf + (size_t)(ng * 2 * 48) * 512 + lane * 8;

    f32x16 acc0 = {}, acc1 = {};
#pragma unroll 4
    for (int ks = 0; ks < 48; ++ks) {
        const short8 a  = *(const short8*)(aP + ks * 512);
        const short8 b0 = *(const short8*)(bP + ks * 512);
        const short8 b1 = *(const short8*)(bP + (48 + ks) * 512);
        acc0 = __builtin_amdgcn_mfma_f32_32x32x16_bf16(a, b0, acc0, 0, 0, 0);
        acc1 = __builtin_amdgcn_mfma_f32_32x32x16_bf16(a, b1, acc1, 0, 0, 0);
    }
#pragma unroll
    for (int jj = 0; jj < 2; ++jj) {
        const int gv = ng * 64 + jj * 32 + colid;
        const int chain = gv / G4;
        const int r = gv % G4;
        const int g = r / HH, u = r % HH;
        const float bv = bias[gv];
        const f32x16& a = jj ? acc1 : acc0;
#pragma unroll
        for (int r16 = 0; r16 < 16; ++r16) {
            const int row = (r16 & 3) + 8 * (r16 >> 2) + 4 * hq;
            const int pos = mt * 32 + row;
            proj[(size_t)pos * PROJ_N + chain * G4 + u * 4 + g] = f2bf(a[r16] + bv);
        }
    }
}

// ---------------------------------------------------------------- LSTM step (MFMA, frag layouts)
// H in A-fragment layout: Hfrag[chain][pt(32)][ks(24)][lane][8].
// W_hh in B-fragment layout: Wfrag[chain*48 + g*12 + utile][ks(24)][lane][8].
// proj in [pos][chain][u][gate] -> one short4 per (pos,unit), prefetched pre-k-loop.
__global__ __launch_bounds__(256) void lstm_step(
        const unsigned short* __restrict__ Wf,
        const unsigned short* __restrict__ proj,
        const unsigned short* __restrict__ Hin,
        unsigned short* __restrict__ Hout,
        float* __restrict__ Cst,
        int s, int wi_min) {
    const int nwi = 4 - wi_min;
    const int cIdx = blockIdx.x / 96;
    const int rem  = blockIdx.x % 96;
    const int pt = rem & 31;
    const int u0 = (rem >> 5) * 128;
    const int dir = (cIdx >= nwi) ? 1 : 0;
    const int wi = wi_min + (dir ? (cIdx - nwi) : cIdx);
    const int chain = dir * 4 + wi;
    const int w = 3 + 2 * wi;
    const int half = wi + 1;
    const int t = dir ? (w - 1 - s) : s;

    const int lane = threadIdx.x & 63;
    const int wv = threadIdx.x >> 6;
    const int colid = lane & 31;
    const int hq = lane >> 5;
    const int uu = u0 + wv * 32 + colid;
    const int m0 = pt * 32;
    const int b = m0 >> 8;
    const int l0 = m0 & 255;

    // ---- prefetch proj (short4 = 4 gates) + C state: independent of MFMAs
    short4v pj[16];
    float cpre[16];
    bool vld[16];
#pragma unroll
    for (int r = 0; r < 16; ++r) {
        const int row = (r & 3) + 8 * (r >> 2) + 4 * hq;  // C/D layout
        const int src = l0 + row + t - half;
        vld[r] = (src >= 0) && (src < LL);
        const int srcc = src < 0 ? 0 : (src > LL - 1 ? LL - 1 : src);
        pj[r] = *(const short4v*)(proj + (size_t)(b * LL + srcc) * PROJ_N + chain * G4 + uu * 4);
        cpre[r] = Cst[(size_t)chain * (NPOS * HH) + (size_t)(m0 + row) * HH + uu];
    }

    const unsigned short* aP = Hin + (size_t)chain * (NPOS * HH) + (size_t)(pt * 24) * 512 + lane * 8;
    const int ut = (u0 >> 5) + wv;
    const unsigned short* bP = Wf + (size_t)((chain * 48 + ut) * 24) * 512 + lane * 8;
    const unsigned short* b1P = bP + (size_t)(12 * 24) * 512;
    const unsigned short* b2P = bP + (size_t)(24 * 24) * 512;
    const unsigned short* b3P = bP + (size_t)(36 * 24) * 512;

    f32x16 acc0 = {}, acc1 = {}, acc2 = {}, acc3 = {};
#pragma unroll 4
    for (int ks = 0; ks < 24; ++ks) {
        const short8 av  = *(const short8*)(aP  + ks * 512);
        const short8 bv0 = *(const short8*)(bP  + ks * 512);
        const short8 bv1 = *(const short8*)(b1P + ks * 512);
        const short8 bv2 = *(const short8*)(b2P + ks * 512);
        const short8 bv3 = *(const short8*)(b3P + ks * 512);
        acc0 = __builtin_amdgcn_mfma_f32_32x32x16_bf16(av, bv0, acc0, 0, 0, 0);
        acc1 = __builtin_amdgcn_mfma_f32_32x32x16_bf16(av, bv1, acc1, 0, 0, 0);
        acc2 = __builtin_amdgcn_mfma_f32_32x32x16_bf16(av, bv2, acc2, 0, 0, 0);
        acc3 = __builtin_amdgcn_mfma_f32_32x32x16_bf16(av, bv3, acc3, 0, 0, 0);
    }

    const int ksp = uu >> 4, khp = (uu >> 3) & 1, jp = uu & 7;
    const size_t hbase = (size_t)chain * (NPOS * HH) + (size_t)(pt * 24 + ksp) * 512 + khp * 256 + jp;
#pragma unroll
    for (int r = 0; r < 16; ++r) {
        const int row = (r & 3) + 8 * (r >> 2) + 4 * hq;
        const size_t hidx = hbase + row * 8;
        if (vld[r]) {
            const float gi = acc0[r] + bf2f((unsigned short)pj[r][0]);
            const float gf = acc1[r] + bf2f((unsigned short)pj[r][1]);
            const float gg = acc2[r] + bf2f((unsigned short)pj[r][2]);
            const float go = acc3[r] + bf2f((unsigned short)pj[r][3]);
            const float iv = 1.f / (1.f + __expf(-gi));
            const float fv = 1.f / (1.f + __expf(-gf));
            const float gv = tanhf(gg);
            const float ov = 1.f / (1.f + __expf(-go));
            const float cn = fv * cpre[r] + iv * gv;
            Cst[(size_t)chain * (NPOS * HH) + (size_t)(m0 + row) * HH + uu] = cn;
            Hout[hidx] = f2bf(ov * tanhf(cn));
        } else {
            Hout[hidx] = Hin[hidx];
        }
    }
}

// ---------------------------------------------------------------- attention + linear head
static __device__ __forceinline__ float hfrag_get(const unsigned short* __restrict__ h,
                                                  int chain, int P, int c) {
    const size_t idx = (size_t)chain * (NPOS * HH)
        + (size_t)((P >> 5) * 24 + (c >> 4)) * 512
        + ((P & 31) + 32 * ((c >> 3) & 1)) * 8 + (c & 7);
    return bf2f(h[idx]);
}

__global__ __launch_bounds__(256) void attn_out_kernel(
        const float* __restrict__ x, const unsigned short* __restrict__ hout,
        const float* __restrict__ lin_w, const float* __restrict__ lin_b,
        float* __restrict__ out) {
    const int P = blockIdx.x;
    const int tid = threadIdx.x;
    const int lane = tid & 63, wid = tid >> 6;
    __shared__ float sc[NWIN][4];
    __shared__ float attn_s[NWIN];
    __shared__ float ov[DD];
    __shared__ float red[NLIN][4];
    const float inv_sqrt_d = 0.03608439182435161f;

    float xr[3];
#pragma unroll
    for (int j = 0; j < 3; ++j) xr[j] = x[(size_t)P * DD + tid + 256 * j];

#pragma unroll
    for (int wi = 0; wi < NWIN; ++wi) {
        float part = 0.f;
#pragma unroll
        for (int j = 0; j < 3; ++j) {
            const int col = tid + 256 * j;
            const float m = (col < HH) ? hfrag_get(hout, wi, P, col)
                                       : hfrag_get(hout, 4 + wi, P, col - HH);
            part = fmaf(xr[j], m, part);
        }
        for (int off = 32; off > 0; off >>= 1) part += __shfl_down(part, off);
        if (lane == 0) sc[wi][wid] = part;
    }
    __syncthreads();
    if (tid == 0) {
        float s[NWIN], mx = -1e30f;
        for (int wi = 0; wi < NWIN; ++wi) {
            s[wi] = (sc[wi][0] + sc[wi][1] + sc[wi][2] + sc[wi][3]) * inv_sqrt_d;
            mx = fmaxf(mx, s[wi]);
        }
        float denom = 0.f;
        for (int wi = 0; wi < NWIN; ++wi) { s[wi] = __expf(s[wi] - mx); denom += s[wi]; }
        for (int wi = 0; wi < NWIN; ++wi) attn_s[wi] = s[wi] / denom;
    }
    __syncthreads();
#pragma unroll
    for (int j = 0; j < 3; ++j) {
        const int col = tid + 256 * j;
        float lv = 0.f;
#pragma unroll
        for (int wi = 0; wi < NWIN; ++wi) {
            const float m = (col < HH) ? hfrag_get(hout, wi, P, col)
                                       : hfrag_get(hout, 4 + wi, P, col - HH);
            lv = fmaf(attn_s[wi], m, lv);
        }
        ov[col] = xr[j] + lv;
    }
    __syncthreads();
    for (int r = 0; r < NLIN; ++r) {
        float part = 0.f;
#pragma unroll
        for (int j = 0; j < 3; ++j) {
            const int col = tid + 256 * j;
            part = fmaf(ov[col], lin_w[r * DD + col], part);
        }
        for (int off = 32; off > 0; off >>= 1) part += __shfl_down(part, off);
        if (lane == 0) red[r][wid] = part;
    }
    __syncthreads();
    if (tid < NLIN)
        out[(size_t)P * NLIN + tid] = red[tid][0] + red[tid][1] + red[tid][2] + red[tid][3] + lin_b[tid];
}

// ---------------------------------------------------------------- launch
extern "C" void kernel_launch(void* const* d_in, const int* in_sizes, int n_in,
                              void* d_out, int out_size, void* d_ws, size_t ws_size,
                              hipStream_t stream) {
    (void)in_sizes; (void)n_in; (void)out_size; (void)ws_size;
    const float* seq   = (const float*)d_in[0];
    const int*   valid = (const int*)d_in[1];
    const float* wih_f = (const float*)d_in[2];
    const float* whh_f = (const float*)d_in[3];
    const float* bih_f = (const float*)d_in[4];
    const float* bhh_f = (const float*)d_in[5];
    const float* wih_b = (const float*)d_in[6];
    const float* whh_b = (const float*)d_in[7];
    const float* bih_b = (const float*)d_in[8];
    const float* bhh_b = (const float*)d_in[9];
    const float* lin_w = (const float*)d_in[10];
    const float* lin_b = (const float*)d_in[11];
    float* out = (float*)d_out;

    // workspace layout (~68.5 MB); cst aliases wfih (dead after proj_mfma)
    float*          x     = (float*)d_ws;                          // 786432 f32
    unsigned short* xfrag = (unsigned short*)(x + NPOS * DD);      // 786432 bf16
    unsigned short* proj  = xfrag + (size_t)NPOS * DD;             // 12582912 bf16
    unsigned short* wfhh  = proj + (size_t)NPOS * PROJ_N;          // 4718592 bf16
    unsigned short* h0    = wfhh + (size_t)4718592;                // 3145728 bf16
    unsigned short* h1    = h0 + (size_t)8 * NPOS * HH;            // 3145728 bf16
    float*          bias  = (float*)(h1 + (size_t)8 * NPOS * HH);  // 12288 f32
    unsigned short* wfih  = (unsigned short*)(bias + PROJ_N);      // 9437184 bf16
    float*          cst   = (float*)wfih;                          // alias: 3145728 f32

    // x + xfrag are contiguous: one zero launch (4718592 B = 294912 float4)
    zero_f4<<<(294912 + 255) / 256, 256, 0, stream>>>((float4*)x, 294912);
    zero_f4<<<(393216 + 255) / 256, 256, 0, stream>>>((float4*)h0, 393216);
    scatter_kernel<<<128, 256, 0, stream>>>(seq, valid, x, xfrag);
    cast_frag<<<384, 256, 0, stream>>>(wih_f, wih_b, wfih, DD);
    cast_frag<<<384, 256, 0, stream>>>(whh_f, whh_b, wfhh, HH);
    bias_kernel<<<48, 256, 0, stream>>>(bih_f, bhh_f, bih_b, bhh_b, bias);
    proj_mfma<<<1536, 256, 0, stream>>>(xfrag, wfih, bias, proj);
    zero_f4<<<(786432 + 255) / 256, 256, 0, stream>>>((float4*)cst, 786432);  // after proj (alias)
    for (int s = 0; s < 9; ++s) {
        const int wi_min = s <= 2 ? 0 : (s <= 4 ? 1 : (s <= 6 ? 2 : 3));
        const int nAct = 2 * (4 - wi_min);
        const unsigned short* hin = (s & 1) ? h1 : h0;
        unsigned short*      hou = (s & 1) ? h0 : h1;
        lstm_step<<<nAct * 96, 256, 0, stream>>>(wfhh, proj, hin, hou, cst, s, wi_min);
    }
    attn_out_kernel<<<NPOS, 256, 0, stream>>>(x, h1, lin_w, lin_b, out);
}